// Round 1
// baseline (82.243 us; speedup 1.0000x reference)
//
#include <hip/hip_runtime.h>

// Problem constants (from reference): N=64, C=256, H=W=56.
#define C_FEAT 256
#define HW 3136      // 56*56 floats per plane
#define HW4 784      // float4 elements per plane

// Step 1: recover the gather index from the permutation matrix.
// W[i*C + j] == 1 iff out channel j comes from input channel i.
// Exactly one i per j -> exactly one writer per idx[j], no race.
__global__ void build_idx_kernel(const float* __restrict__ W, int* __restrict__ idx) {
    int i = blockIdx.x;    // source channel (row of W)
    int j = threadIdx.x;   // dest channel (col of W)
    if (W[i * C_FEAT + j] > 0.5f) idx[j] = i;
}

// Step 2: permuted plane copy. One block per output plane (n, j).
// Planes are contiguous 12544-byte chunks, 16B-aligned -> float4 copy.
__global__ void __launch_bounds__(256)
channel_shuffle_kernel(const float4* __restrict__ x, const int* __restrict__ idx,
                       float4* __restrict__ out) {
    int plane = blockIdx.x;        // n*C + j
    int n = plane >> 8;            // / 256
    int j = plane & 255;           // % 256
    int src_plane = (n << 8) + idx[j];

    const float4* __restrict__ xs = x + (size_t)src_plane * HW4;
    float4* __restrict__ od = out + (size_t)plane * HW4;

    #pragma unroll
    for (int k = 0; k < 4; ++k) {
        int t = threadIdx.x + k * 256;
        if (t < HW4) od[t] = xs[t];
    }
}

extern "C" void kernel_launch(void* const* d_in, const int* in_sizes, int n_in,
                              void* d_out, int out_size, void* d_ws, size_t ws_size,
                              hipStream_t stream) {
    const float* x = (const float*)d_in[0];   // [64, 256, 56, 56] f32
    const float* W = (const float*)d_in[1];   // [256, 256] f32 permutation matrix
    float* out = (float*)d_out;
    int* idx = (int*)d_ws;                    // 256 ints of scratch

    build_idx_kernel<<<dim3(C_FEAT), dim3(C_FEAT), 0, stream>>>(W, idx);

    const int n_planes = 64 * C_FEAT;         // 16384 output planes
    channel_shuffle_kernel<<<dim3(n_planes), dim3(256), 0, stream>>>(
        (const float4*)x, idx, (float4*)out);
}

// Round 3
// 66.235 us; speedup vs baseline: 1.2417x; 1.2417x over previous
//
#include <hip/hip_runtime.h>

// N=64, C=256, H=W=56 -> plane = 3136 floats = 784 float4.
#define C_FEAT 256
#define HW4 784
#define TOTAL4 (64 * 256 * HW4)   // 12,845,056 float4 elements
#define HALF4 (TOTAL4 / 2)        // 6,422,528

typedef float f32x4 __attribute__((ext_vector_type(4)));  // native vector: OK for nontemporal builtin

// Recover gather index from permutation matrix: W[i*C+j]==1 iff out channel j
// sources input channel i. Exactly one writer per idx[j] -> race-free.
__global__ void build_idx_kernel(const float* __restrict__ W, int* __restrict__ idx) {
    int i = blockIdx.x;    // source channel (row)
    int j = threadIdx.x;   // dest channel (col)
    if (W[i * C_FEAT + j] > 0.5f) idx[j] = i;
}

// Flat permuted copy: each thread moves 2 float4s, exact grid (no tail).
// For flat float4 index g: plane = g/784, j = plane & 255,
// src_g = g + (idx[j] - j)*784  (same n, same intra-plane offset, swapped channel).
__global__ void __launch_bounds__(256)
shuffle_flat_kernel(const f32x4* __restrict__ x, const int* __restrict__ idx,
                    f32x4* __restrict__ out) {
    unsigned g = blockIdx.x * 256u + threadIdx.x;

    #pragma unroll
    for (int it = 0; it < 2; ++it) {
        unsigned plane = g / HW4;                 // magic-mul, no real divide
        unsigned j = plane & (C_FEAT - 1);
        int d = idx[j] - (int)j;                  // channel displacement
        f32x4 v = x[(int)g + d * HW4];
        __builtin_nontemporal_store(v, &out[g]);  // evict-first: keep x in L3
        g += HALF4;
    }
}

extern "C" void kernel_launch(void* const* d_in, const int* in_sizes, int n_in,
                              void* d_out, int out_size, void* d_ws, size_t ws_size,
                              hipStream_t stream) {
    const float* x = (const float*)d_in[0];   // [64,256,56,56] f32
    const float* W = (const float*)d_in[1];   // [256,256] f32 permutation
    float* out = (float*)d_out;
    int* idx = (int*)d_ws;                    // 256 ints scratch

    build_idx_kernel<<<dim3(C_FEAT), dim3(C_FEAT), 0, stream>>>(W, idx);

    const int blocks = HALF4 / 256;           // 25088, exact
    shuffle_flat_kernel<<<dim3(blocks), dim3(256), 0, stream>>>(
        (const f32x4*)x, idx, (f32x4*)out);
}